// Round 1
// baseline (700.139 us; speedup 1.0000x reference)
//
#include <hip/hip_runtime.h>
#include <hip/hip_bf16.h>

// Cosine similarity of each pixel's C=128 vector with its 8 neighbors (3x3,
// zero-padded), minus 1.  Identity used:
//   sim(p) = dot(xn_p, boxsum3x3(xn)_p)      (self term included, = 1)
// so out = dot(xn, B) - 1 with B the separable 3x3 box sum of normalized x.
// Single pass over the 512 MiB input -> HBM-read-bound (~85 us floor).

#define HH 1024
#define WW 1024
#define C4 32          // float4 chunks per pixel (128 channels)
#define SOUT 64        // output columns per strip
#define SHALO (SOUT + 2)
#define RROWS 32       // output rows per block
#define NT 512
#define NSTAGE ((SHALO * C4 + NT - 1) / NT)   // 5 (last partial)
#define OWN ((SOUT * C4) / NT)                // 4 owned (x,chunk) per thread

__device__ __forceinline__ float dot4(float4 a, float4 b) {
    return fmaf(a.x, b.x, fmaf(a.y, b.y, fmaf(a.z, b.z, a.w * b.w)));
}

__global__ __launch_bounds__(NT, 4)
void cos_sim_kernel(const float4* __restrict__ in, float* __restrict__ out) {
    // One row of normalized pixels (with x halo), [pixel][chunk] layout.
    __shared__ float4 xrow[SHALO * C4];   // 66*32*16B = 33 KB

    const int t   = threadIdx.x;
    const int c4  = t & 31;       // channel chunk within pixel
    const int xo0 = t >> 5;       // base owned output col (0..15), +16*i
    const int x0  = blockIdx.x * SOUT;   // strip base (output cols)
    const int r0  = blockIdx.y * RROWS;  // row-chunk base

    // Rolling per-owned-pixel state: H of previous input row, xn of previous
    // input row, and the partial accumulator for output row (y-1).
    float4 Hprev[OWN], XNprev[OWN];
    float  accP[OWN];
#pragma unroll
    for (int i = 0; i < OWN; ++i) {
        Hprev[i]  = make_float4(0.f, 0.f, 0.f, 0.f);
        XNprev[i] = make_float4(0.f, 0.f, 0.f, 0.f);
        accP[i]   = 0.f;
    }

    for (int y = r0 - 1; y <= r0 + RROWS; ++y) {
        const bool rowOK = (y >= 0) && (y < HH);

        // ---- stage: load row y (coalesced float4), all loads in flight ----
        float4 v[NSTAGE];
#pragma unroll
        for (int i = 0; i < NSTAGE; ++i) {
            const int idx = t + i * NT;          // (x_in, chunk) flat
            float4 val = make_float4(0.f, 0.f, 0.f, 0.f);
            if (idx < SHALO * C4) {
                const int xi = idx >> 5;         // 0..65 -> global x = x0-1+xi
                const int gx = x0 - 1 + xi;
                if (rowOK && gx >= 0 && gx < WW) {
                    val = in[(size_t)(y * WW + gx) * C4 + (idx & 31)];
                }
            }
            v[i] = val;
        }

        // ---- normalize: per-pixel norm via 32-lane xor reduce, write LDS ----
#pragma unroll
        for (int i = 0; i < NSTAGE; ++i) {
            const int idx = t + i * NT;
            float s = dot4(v[i], v[i]);
            s += __shfl_xor(s, 1);
            s += __shfl_xor(s, 2);
            s += __shfl_xor(s, 4);
            s += __shfl_xor(s, 8);
            s += __shfl_xor(s, 16);
            const float inv = 1.0f / fmaxf(sqrtf(s), 1e-8f);
            if (idx < SHALO * C4) {
                float4 w;
                w.x = v[i].x * inv; w.y = v[i].y * inv;
                w.z = v[i].z * inv; w.w = v[i].w * inv;
                xrow[idx] = w;
            }
        }
        __syncthreads();

        // ---- compute: H_y in registers, pair with rolling xn/H state ----
#pragma unroll
        for (int i = 0; i < OWN; ++i) {
            const int xo = xo0 + 16 * i;                // output col in strip
            const float4 a = xrow[(xo    ) * C4 + c4];  // x-1
            const float4 b = xrow[(xo + 1) * C4 + c4];  // x   (center)
            const float4 r = xrow[(xo + 2) * C4 + c4];  // x+1
            float4 Hc;
            Hc.x = a.x + b.x + r.x; Hc.y = a.y + b.y + r.y;
            Hc.z = a.z + b.z + r.z; Hc.w = a.w + b.w + r.w;

            // out(y-1) completes: += dot(xn_{y-1}, H_y)
            float fin = accP[i] + dot4(XNprev[i], Hc);
            // out(y) partial: dot(xn_y, H_{y-1}) + dot(xn_y, H_y)
            accP[i]   = dot4(b, Hprev[i]) + dot4(b, Hc);
            XNprev[i] = b;
            Hprev[i]  = Hc;

            if (y > r0) {   // uniform branch: finalize row y-1 (in range)
                fin += __shfl_xor(fin, 1);
                fin += __shfl_xor(fin, 2);
                fin += __shfl_xor(fin, 4);
                fin += __shfl_xor(fin, 8);
                fin += __shfl_xor(fin, 16);
                if (c4 == 0) {
                    out[(size_t)(y - 1) * WW + x0 + xo] = fin - 1.0f;
                }
            }
        }
        __syncthreads();   // protect xrow before next row's staging writes
    }
}

extern "C" void kernel_launch(void* const* d_in, const int* in_sizes, int n_in,
                              void* d_out, int out_size, void* d_ws, size_t ws_size,
                              hipStream_t stream) {
    const float4* in = (const float4*)d_in[0];
    float* out = (float*)d_out;
    dim3 grid(WW / SOUT, HH / RROWS);   // 16 x 32 = 512 blocks
    cos_sim_kernel<<<grid, NT, 0, stream>>>(in, out);
}